// Round 11
// baseline (479.052 us; speedup 1.0000x reference)
//
#include <hip/hip_runtime.h>
#include <string.h>

// TopographicIntentMap R11: spike-bitmask algorithm change.
// R6-R10 showed the per-entry LDS gather costs ~30-43 VALU cyc no matter the
// encoding. Replace it: acc_t = sum of spike vectors, so
//   rec_t[o] = REC (running, in REGISTERS), REC += Delta_t[o],
//   Delta[o] = sum_j w[o][j] * s_t[j],  s in {0,1}.
// With lane=batch, neuron j's spikes across the 64 batches ARE one __ballot
// mask, and v_cndmask_b32 with an SGPR-pair mask selects bit L for lane L
// natively. Per tick: phase1 = update v for 9 rows, ballot, write 144 u64
// masks to LDS (1.2KB, double-buffered); ONE barrier; phase2 = stream CSR
// (R7's proven mov-free depth-2 vector pipeline), per entry:
//   v_add(addr) + ds_read_b64(uniform mask) + 2x readfirstlane +
//   v_cndmask(0,w) + v_cvt_f64_f32 + v_add_f64   (~16 cyc, no gather)
// Numerics: exact-f64 class identical to R4-R10 (absmax 0 every round):
// cvt(cndmask)=0.0 or (double)w exactly; v*(1-s) == select(v,0) exactly;
// zero pads add +0.0; incremental REC is f64-reassociation class (~1e-16).

#define NN 144
#define NE 115
#define NB 64            // batches per block (= lanes)
#define RPW 9            // rows per wave: 16*9 = 144
#define THREADS 1024

// ws layout: int rowptr[145] at 0; padded (x4) CSR entries at byte 4096,
// 8B each: {u32 colOff=col*8, f32 w}; 16-entry zero tail.
#define CSR_BYTE_OFF 4096

__device__ __forceinline__ float u2f(unsigned u) {
    float f; memcpy(&f, &u, 4); return f;
}

__global__ void prep_kernel(const float* __restrict__ W_rec,
                            int* __restrict__ wsI, char* __restrict__ wsB) {
    __shared__ int cnt[NN];
    __shared__ int rp[NN + 1];
    int t = threadIdx.x;

    if (t < NN) {
        int c = 0;
        for (int j = 0; j < NN; ++j) c += (W_rec[t * NN + j] != 0.0f);
        cnt[t] = c;
    }
    __syncthreads();
    if (t == 0) {
        int s = 0; rp[0] = 0;
        for (int o = 0; o < NN; ++o) { s += (cnt[o] + 3) & ~3; rp[o + 1] = s; }
    }
    __syncthreads();
    if (t <= NN) wsI[t] = rp[t];
    char* base = wsB + CSR_BYTE_OFF;
    if (t < NN) {
        int p = rp[t];
        for (int j = 0; j < NN; ++j) {
            float w = W_rec[t * NN + j];
            if (w != 0.0f) {
                *(unsigned*)(base + 8 * (size_t)p) = (unsigned)j * 8u;  // mask byte off
                *(float*)(base + 8 * (size_t)p + 4) = w;
                ++p;
            }
        }
        for (; p < rp[t + 1]; ++p) {                 // zero-weight pads (exact)
            *(unsigned*)(base + 8 * (size_t)p)  = 0u;
            *(float*)(base + 8 * (size_t)p + 4) = 0.0f;
        }
    }
    if (t < 16) {                                    // pipeline-overrun tail
        int p = rp[NN] + t;
        *(unsigned*)(base + 8 * (size_t)p)  = 0u;
        *(float*)(base + 8 * (size_t)p + 4) = 0.0f;
    }
}

// select w where this lane's bit is set in (mlo,mhi), else 0.0f.
__device__ __forceinline__ float selw(float w, unsigned mlo, unsigned mhi) {
    unsigned long long mu =
        (((unsigned long long)(unsigned)__builtin_amdgcn_readfirstlane((int)mhi)) << 32) |
        (unsigned)__builtin_amdgcn_readfirstlane((int)mlo);
    float r;
    asm("v_cndmask_b32 %0, 0, %1, %2" : "=v"(r) : "v"(w), "s"(mu));
    return r;
}

// 4 entries from two uint4 regs: {colOff,w} pairs; masked f64 accumulation.
#define MSEL4(S0, S1)                                                   \
    {                                                                   \
        uint2 m0 = *(const uint2*)(mkB + ((S0).x + mOff));              \
        uint2 m1 = *(const uint2*)(mkB + ((S0).z + mOff));              \
        uint2 m2 = *(const uint2*)(mkB + ((S1).x + mOff));              \
        uint2 m3 = *(const uint2*)(mkB + ((S1).z + mOff));              \
        rec0 += (double)selw(u2f((S0).y), m0.x, m0.y);                  \
        rec1 += (double)selw(u2f((S0).w), m1.x, m1.y);                  \
        rec0 += (double)selw(u2f((S1).y), m2.x, m2.y);                  \
        rec1 += (double)selw(u2f((S1).w), m3.x, m3.y);                  \
    }

__global__ __launch_bounds__(THREADS) void snn_kernel(
        const int*   __restrict__ actions,
        const float* __restrict__ spk,      // [B,8,115]
        const float* __restrict__ W_inh,    // [144,115]
        const int*   __restrict__ wsI,      // padded rowptr
        const uint4* __restrict__ csrQ,     // 2 entries per uint4
        const int*   __restrict__ nt_ptr,
        float*       __restrict__ out,      // [B,115]
        int B) {
    __shared__ unsigned long long maskL[2][NN];   // 2.3KB spike masks
    __shared__ float nbF[NE][NB + 1];             // neighbor sums (pre-loop)
    __shared__ int   rpL[NN + 1];

    const char* mkB = (const char*)maskL;

    const int t    = threadIdx.x;
    const int lane = t & 63;
    const int wid  = t >> 6;
    const int b0   = blockIdx.x * NB;
    const int b    = b0 + lane;
    const int ticks = *nt_ptr;
    const int R0   = wid * RPW;

    // opaque per-lane zero: keeps the CSR stream on the vector VMEM path
    int vz;
    asm volatile("v_mov_b32 %0, 0" : "=v"(vz));

    if (t <= NN) rpL[t] = wsI[t];

    // stage neighbor sums into nbF[e][bb]
    for (int p = t; p < NB * NE; p += THREADS) {
        int bb = p / NE;
        int e  = p - bb * NE;
        float s = 0.0f;
        if (b0 + bb < B) {
            const float* sp = spk + ((size_t)(b0 + bb) * 8) * NE + e;
            #pragma unroll
            for (int n = 0; n < 8; ++n) s += sp[n * NE];
        }
        nbF[e][bb] = s;
    }
    __syncthreads();

    // per-row drives (fp64, e ascending — unchanged association)
    const int R0s = __builtin_amdgcn_readfirstlane(R0);
    double drv[RPW];
    {
        int a = (b < B) ? actions[b] : 4;
        int cell = (a == 0) ? 5 : (a == 1) ? 1 : (a == 2) ? 3 : (a == 3) ? 7 : 4;
        int cs = cell * 16;
        #pragma unroll
        for (int r = 0; r < RPW; ++r) {
            double inh = 0.0;
            for (int e = 0; e < NE; ++e)
                inh += (double)nbF[e][lane] * (double)W_inh[(R0s + r) * NE + e];
            int o = R0 + r;
            double ic = (o >= cs && o < cs + 16) ? 5.0 : 0.0;
            drv[r] = 0.5 * ic - 0.5 * inh;
        }
    }

    int sk0[RPW], sk1[RPW];
    #pragma unroll
    for (int r = 0; r < RPW; ++r) {
        sk0[r] = __builtin_amdgcn_readfirstlane(rpL[R0 + r]);
        sk1[r] = __builtin_amdgcn_readfirstlane(rpL[R0 + r + 1]);
    }
    const uint4* pBase = csrQ + (sk0[0] >> 1) + vz;   // per-lane ptr (VMEM)

    double v[RPW], REC[RPW];
    float  accv[RPW];
    #pragma unroll
    for (int r = 0; r < RPW; ++r) { v[r] = 0.0; REC[r] = 0.0; accv[r] = 0.0f; }

    for (int tk = 0; tk < ticks; ++tk) {
        // phase 1: LIF update for my 9 rows using running REC; ballot spikes
        #pragma unroll
        for (int r = 0; r < RPW; ++r) {
            const int o = R0 + r;
            double rec = REC[r];
            double x = drv[r] + 0.3 * ((o < NE) ? rec : -rec);
            double vv = v[r];
            vv += (x - vv) * 0.5;
            bool sp = (vv >= 1.0);
            unsigned long long m = __ballot(sp);
            if (lane == r) maskL[tk & 1][R0 + r] = m;
            v[r] = sp ? 0.0 : vv;          // == vv*(1-s) exactly
            accv[r] += sp ? 1.0f : 0.0f;
        }
        __syncthreads();   // masks of tick tk visible to all waves

        // phase 2: REC += Delta via CSR stream + cndmask selects
        const unsigned mOff = (unsigned)((tk & 1) * (NN * 8));
        const uint4* p = pBase;
        uint4 SA0 = p[0], SA1 = p[1];
        uint4 SB0 = p[2], SB1 = p[3];

        #pragma unroll
        for (int r = 0; r < RPW; ++r) {
            double rec0 = 0.0, rec1 = 0.0;
            int k = sk0[r];
            const int kend = sk1[r];
            while (k + 8 <= kend) {          // 8 entries/iter, zero-mov steady state
                MSEL4(SA0, SA1);
                SA0 = p[4]; SA1 = p[5];
                MSEL4(SB0, SB1);
                SB0 = p[6]; SB1 = p[7];
                p += 4; k += 8;
            }
            if (k < kend) {                  // one leftover 4-entry chunk
                MSEL4(SA0, SA1);
                SA0 = SB0; SA1 = SB1;
                SB0 = p[4]; SB1 = p[5];
                p += 2;
            }
            REC[r] += rec0 + rec1;           // f64-reassociation class (safe)
        }
    }

    if (b < B) {
        #pragma unroll
        for (int r = 0; r < RPW; ++r) {
            int o = R0 + r;
            if (o < NE) out[(size_t)b * NE + o] = accv[r];
        }
    }
}

extern "C" void kernel_launch(void* const* d_in, const int* in_sizes, int n_in,
                              void* d_out, int out_size, void* d_ws, size_t ws_size,
                              hipStream_t stream) {
    const int*   actions = (const int*)  d_in[0];
    const float* spk     = (const float*)d_in[1];
    const float* W_rec   = (const float*)d_in[2];
    const float* W_inh   = (const float*)d_in[3];
    const int*   nt      = (const int*)  d_in[4];
    float* out = (float*)d_out;
    int B = in_sizes[0];

    int*  wsI = (int*)d_ws;
    char* wsB = (char*)d_ws;
    const uint4* csrQ = (const uint4*)(wsB + CSR_BYTE_OFF);

    prep_kernel<<<1, 256, 0, stream>>>(W_rec, wsI, wsB);
    int nblocks = (B + NB - 1) / NB;
    snn_kernel<<<nblocks, THREADS, 0, stream>>>(actions, spk, W_inh, wsI, csrQ,
                                                nt, out, B);
}

// Round 12
// 392.631 us; speedup vs baseline: 1.2201x; 1.2201x over previous
//
#include <hip/hip_runtime.h>
#include <string.h>

// TopographicIntentMap R12: R7 skeleton (362us, best) + the two mechanisms
// that R9/R10 validated numerically but sank structurally:
//  (1) dual f64 accumulators, alternating entries (rec0: 0,2,..; rec1: 1,3,..)
//      -> halves the serial f64-FMA latency chain (R7: 8 chained FMAs/iter).
//      Ordering safety proven empirically: R9/R11 passed (absmax 0) with
//      different associations of the same exact-f64 sums.
//  (2) acc in LDS as f64 (exact: integers <= 30), double-buffered -> the
//      per-entry acc cvt disappears; gather = lane-consecutive ds_read_b64
//      (2-way aliasing = free, m136). Weight stays plain f32 in the stream
//      (ONE cvt/entry, no 64-bit pair assembly -- R10's mistake).
// Hazards avoided: one tick body (R9 spills), one AoS stream (R8 latency),
// no packing (R10 movs), no cross-unit per-entry ops (R11 chain).
// Per-entry VALU: v_add(addr) + v_cvt_f64_f32(w) + v_fma_f64 = ~10cy.
// Numerics: exact-f64 pipeline class of R3-R11 (absmax 0 in all 9 rounds).

#define NN 144
#define NE 115
#define NB 64            // batches per block (= lanes)
#define RPW 9            // rows per wave: 16*9 = 144
#define THREADS 1024

// ws layout: int rowptr[145] at 0; padded (x4) CSR entries at byte 4096,
// 8B each: {u32 colByte = col*512 (f64 row stride 64*8), f32 w}; 16-entry tail.
#define CSR_BYTE_OFF 4096

__device__ __forceinline__ float u2f(unsigned u) {
    float f; memcpy(&f, &u, 4); return f;
}

__global__ void prep_kernel(const float* __restrict__ W_rec,
                            int* __restrict__ wsI, char* __restrict__ wsB) {
    __shared__ int cnt[NN];
    __shared__ int rp[NN + 1];
    int t = threadIdx.x;

    if (t < NN) {
        int c = 0;
        for (int j = 0; j < NN; ++j) c += (W_rec[t * NN + j] != 0.0f);
        cnt[t] = c;
    }
    __syncthreads();
    if (t == 0) {
        int s = 0; rp[0] = 0;
        for (int o = 0; o < NN; ++o) { s += (cnt[o] + 3) & ~3; rp[o + 1] = s; }
    }
    __syncthreads();
    if (t <= NN) wsI[t] = rp[t];
    char* base = wsB + CSR_BYTE_OFF;
    if (t < NN) {
        int p = rp[t];
        for (int j = 0; j < NN; ++j) {
            float w = W_rec[t * NN + j];
            if (w != 0.0f) {
                *(unsigned*)(base + 8 * (size_t)p) = (unsigned)j * 512u;
                *(float*)(base + 8 * (size_t)p + 4) = w;
                ++p;
            }
        }
        for (; p < rp[t + 1]; ++p) {                 // zero-weight pads (exact)
            *(unsigned*)(base + 8 * (size_t)p)  = 0u;
            *(float*)(base + 8 * (size_t)p + 4) = 0.0f;
        }
    }
    if (t < 16) {                                    // pipeline-overrun tail
        int p = rp[NN] + t;
        *(unsigned*)(base + 8 * (size_t)p)  = 0u;
        *(float*)(base + 8 * (size_t)p + 4) = 0.0f;
    }
}

// 4 entries from two uint4 regs: {colByte,w}; dual alternating f64 accs.
#define GFMA4(S0, S1)                                                   \
    {                                                                   \
        double a0 = *(const double*)(ldsB + ((S0).x + lro));            \
        double a1 = *(const double*)(ldsB + ((S0).z + lro));            \
        double a2 = *(const double*)(ldsB + ((S1).x + lro));            \
        double a3 = *(const double*)(ldsB + ((S1).z + lro));            \
        rec0 += (double)u2f((S0).y) * a0;                               \
        rec1 += (double)u2f((S0).w) * a1;                               \
        rec0 += (double)u2f((S1).y) * a2;                               \
        rec1 += (double)u2f((S1).w) * a3;                               \
    }

__global__ __launch_bounds__(THREADS) void snn_kernel(
        const int*   __restrict__ actions,
        const float* __restrict__ spk,      // [B,8,115]
        const float* __restrict__ W_inh,    // [144,115]
        const int*   __restrict__ wsI,      // padded rowptr
        const uint4* __restrict__ csrQ,     // 2 entries per uint4
        const int*   __restrict__ nt_ptr,
        float*       __restrict__ out,      // [B,115]
        int B) {
    __shared__ double accD[2 * NN * NB];    // 147456 B, double-buffered f64
    __shared__ int    rpL[NN + 1];

    float* nbF = (float*)&accD[NN * NB];    // [NE][65] alias, pre-loop only
    const char* ldsB = (const char*)accD;   // gather base (compile-time LDS)

    const int t    = threadIdx.x;
    const int lane = t & 63;
    const int wid  = t >> 6;
    const int b0   = blockIdx.x * NB;
    const int b    = b0 + lane;
    const int ticks = *nt_ptr;
    const int R0   = wid * RPW;
    const unsigned laneB8 = (unsigned)lane * 8u;

    // opaque per-lane zero: keeps the CSR stream on the vector VMEM path
    int vz;
    asm volatile("v_mov_b32 %0, 0" : "=v"(vz));

    if (t <= NN) rpL[t] = wsI[t];

    // stage neighbor sums into nbF[e][bb]
    for (int p = t; p < NB * NE; p += THREADS) {
        int bb = p / NE;
        int e  = p - bb * NE;
        float s = 0.0f;
        if (b0 + bb < B) {
            const float* sp = spk + ((size_t)(b0 + bb) * 8) * NE + e;
            #pragma unroll
            for (int n = 0; n < 8; ++n) s += sp[n * NE];
        }
        nbF[e * (NB + 1) + bb] = s;
    }
    for (int i = t; i < NN * NB; i += THREADS) accD[i] = 0.0;
    __syncthreads();

    // per-row drives (fp64, e ascending — unchanged association)
    const int R0s = __builtin_amdgcn_readfirstlane(R0);
    double drv[RPW];
    {
        int a = (b < B) ? actions[b] : 4;
        int cell = (a == 0) ? 5 : (a == 1) ? 1 : (a == 2) ? 3 : (a == 3) ? 7 : 4;
        int cs = cell * 16;
        #pragma unroll
        for (int r = 0; r < RPW; ++r) {
            double inh = 0.0;
            for (int e = 0; e < NE; ++e)
                inh += (double)nbF[e * (NB + 1) + lane]
                     * (double)W_inh[(R0s + r) * NE + e];
            int o = R0 + r;
            double ic = (o >= cs && o < cs + 16) ? 5.0 : 0.0;
            drv[r] = 0.5 * ic - 0.5 * inh;
        }
    }

    int sk0[RPW], sk1[RPW];
    #pragma unroll
    for (int r = 0; r < RPW; ++r) {
        sk0[r] = __builtin_amdgcn_readfirstlane(rpL[R0 + r]);
        sk1[r] = __builtin_amdgcn_readfirstlane(rpL[R0 + r + 1]);
    }
    const uint4* pBase = csrQ + (sk0[0] >> 1) + vz;   // per-lane ptr (VMEM)

    double v[RPW];
    float  accv[RPW];
    #pragma unroll
    for (int r = 0; r < RPW; ++r) { v[r] = 0.0; accv[r] = 0.0f; }

    for (int tk = 0; tk < ticks; ++tk) {
        __syncthreads();   // prev tick's acc writes (or initial zeros) visible
        const unsigned rbOff = (tk & 1) ? (unsigned)(NN * NB * 8) : 0u;
        const unsigned lro   = laneB8 + rbOff;          // folded gather offset
        double* __restrict__ Wb = accD + ((tk & 1) ? 0 : NN * NB);

        // prime: SA = entries k..k+3, SB = k+4..k+7 (flat stream)
        const uint4* p = pBase;
        uint4 SA0 = p[0], SA1 = p[1];
        uint4 SB0 = p[2], SB1 = p[3];

        #pragma unroll
        for (int r = 0; r < RPW; ++r) {
            const int o = R0 + r;
            double rec0 = 0.0, rec1 = 0.0;
            int k = sk0[r];
            const int kend = sk1[r];
            // steady state: 2 chunks (8 entries)/iter, zero rotation movs
            while (k + 8 <= kend) {
                GFMA4(SA0, SA1);
                SA0 = p[4]; SA1 = p[5];          // entries k+8..k+11
                GFMA4(SB0, SB1);
                SB0 = p[6]; SB1 = p[7];          // entries k+12..k+15
                p += 4; k += 8;
            }
            if (k < kend) {                      // one leftover 4-entry chunk
                GFMA4(SA0, SA1);
                SA0 = SB0; SA1 = SB1;            // once-per-odd-row movs
                SB0 = p[4]; SB1 = p[5];
                p += 2;
            }
            // invariant: SA = next row's first chunk, SB = second
            double rec = rec0 + rec1;            // exact-f64 class (validated)
            double x = drv[r] + 0.3 * ((o < NE) ? rec : -rec);
            double vv = v[r];
            vv += (x - vv) * 0.5;
            double s = (vv >= 1.0) ? 1.0 : 0.0;
            vv *= (1.0 - s);
            v[r] = vv;
            accv[r] += (float)s;
            Wb[(o << 6) + lane] = (double)accv[r];   // exact integer
        }
    }

    if (b < B) {
        #pragma unroll
        for (int r = 0; r < RPW; ++r) {
            int o = R0 + r;
            if (o < NE) out[(size_t)b * NE + o] = accv[r];
        }
    }
}

extern "C" void kernel_launch(void* const* d_in, const int* in_sizes, int n_in,
                              void* d_out, int out_size, void* d_ws, size_t ws_size,
                              hipStream_t stream) {
    const int*   actions = (const int*)  d_in[0];
    const float* spk     = (const float*)d_in[1];
    const float* W_rec   = (const float*)d_in[2];
    const float* W_inh   = (const float*)d_in[3];
    const int*   nt      = (const int*)  d_in[4];
    float* out = (float*)d_out;
    int B = in_sizes[0];

    int*  wsI = (int*)d_ws;
    char* wsB = (char*)d_ws;
    const uint4* csrQ = (const uint4*)(wsB + CSR_BYTE_OFF);

    prep_kernel<<<1, 256, 0, stream>>>(W_rec, wsI, wsB);
    int nblocks = (B + NB - 1) / NB;
    snn_kernel<<<nblocks, THREADS, 0, stream>>>(actions, spk, W_inh, wsI, csrQ,
                                                nt, out, B);
}